// Round 3
// baseline (3431.942 us; speedup 1.0000x reference)
//
#include <hip/hip_runtime.h>
#include <stdint.h>

#define NTAGS 512
#define STAG 510
#define PTAG 511
#define SEQ 512
#define L2E 1.4426950408889634f
#define LN2 0.6931471805599453f

typedef int   v8i __attribute__((ext_vector_type(8)));
typedef float v4f __attribute__((ext_vector_type(4)));

// max with a DPP-permuted copy (ctrl must be a literal)
#define DPPMAX(X, CTRL) fmaxf((X), __int_as_float(__builtin_amdgcn_update_dpp( \
    0, __float_as_int(X), (CTRL), 0xF, 0xF, false)))
// 0xB1 = quad_perm xor1 ; 0x4E = quad_perm xor2 ; 0x141 = row_half_mirror (xor7) ; 0x140 = row_mirror (xor15)

// ---------------- main: 8 WGs x 16 batches, 512 threads (8 waves) ----------------
__global__ __launch_bounds__(512, 2) void crf_main_k(
    const float* __restrict__ inp, const float* __restrict__ trans,
    float* __restrict__ part)
{
    __shared__ uint8_t aqb[2*8192];
    __shared__ uint8_t scb[2*256];
    __shared__ int     mxp[2*16];
    __shared__ float   mxb[16*8];
    __shared__ float   ssum[16*8];
    __shared__ float   Gb[16];

    const int tid = threadIdx.x;
    const int w = tid >> 6, l = tid & 63, c = l & 15, g = l >> 4;
    const int wg = blockIdx.x;
    const int b0 = g * 4;

    // ---- build persistent B fragments: E = exp(trans) -> MX-fp6 e2m3, k-permuted ----
    // Permutation pi (k-block KB, idx in [0,32)): p = (KB>>1)*64 + (idx&3)*16 + (KB&1)*8 + (idx>>2)
    v8i Bf[16];
    int esc[4];
    #pragma unroll
    for (int i = 0; i < 4; ++i) {
        const int n = (w*4 + i)*16 + c;
        const float* row = trans + n*NTAGS;
        uint32_t es_i = 0;
        #pragma unroll
        for (int kk = 0; kk < 4; ++kk) {
            const int KB = kk*4 + g;
            const int wq = KB >> 1, h = KB & 1;
            float mxl = -3.0e38f;
            #pragma unroll
            for (int k = 0; k < 32; ++k) {
                int p = wq*64 + (k & 3)*16 + h*8 + (k >> 2);
                mxl = fmaxf(mxl, row[p]);
            }
            int e = (int)floorf(mxl * L2E - 2.90689059f);   // blockmax -> (3.75, 7.5]
            int byt = e + 127; byt = byt < 0 ? 0 : (byt > 254 ? 254 : byt);
            float eeff = (float)(byt - 127);
            uint32_t out[6] = {0u,0u,0u,0u,0u,0u};
            #pragma unroll
            for (int k = 0; k < 32; ++k) {
                int p = wq*64 + (k & 3)*16 + h*8 + (k >> 2);
                float q = exp2f(row[p] * L2E - eeff);
                int code;
                if      (q < 2.0f) code = (int)(q * 8.0f + 0.5f);
                else if (q < 4.0f) code = 16 + (int)((q - 2.0f) * 4.0f + 0.5f);
                else               code = 24 + (int)((q - 4.0f) * 2.0f + 0.5f);
                code = code > 31 ? 31 : code;
                int bp = 6*k, d = bp >> 5, off = bp & 31;
                out[d] |= (uint32_t)code << off;
                if (off > 26) out[d+1] |= (uint32_t)code >> (32 - off);
            }
            v8i bv;
            bv[0]=(int)out[0]; bv[1]=(int)out[1]; bv[2]=(int)out[2];
            bv[3]=(int)out[3]; bv[4]=(int)out[4]; bv[5]=(int)out[5];
            bv[6]=0; bv[7]=0;
            Bf[i*4 + kk] = bv;
            es_i |= (uint32_t)byt << (8*kk);
        }
        esc[i] = (int)es_i;
    }

    const float* ep[4];
    #pragma unroll
    for (int j = 0; j < 4; ++j)
        ep[j] = inp + (size_t)(wg*16 + b0 + j) * (SEQ*NTAGS) + w*64 + c;   // row 0

// quantize 4 values (i=0..3) of batch b0+J into AQ/SC with fold RJ.
#define QUANT_STORE(J, V0, V1, V2, V3, RJ, AQ, SC) do { \
    float bm_ = fmaxf(fmaxf(V0, V1), fmaxf(V2, V3)); \
    bm_ = DPPMAX(bm_, 0xB1); bm_ = DPPMAX(bm_, 0x4E); bm_ = DPPMAX(bm_, 0x141); \
    int be_ = (int)((__float_as_uint(bm_) >> 23) & 255u) - 127; \
    be_ = be_ < -60 ? -60 : be_; \
    float qs_ = __int_as_float((uint32_t)(133 - be_) << 23); \
    int t_ = __builtin_amdgcn_cvt_pk_fp8_f32((V0)*qs_, (V1)*qs_, 0, false); \
    t_ = __builtin_amdgcn_cvt_pk_fp8_f32((V2)*qs_, (V3)*qs_, t_, true); \
    int bb_ = b0 + (J); \
    ((uint32_t*)(AQ))[bb_*128 + (((w*4 + (c>>2)) ^ (bb_ & 7)) << 2) + (c & 3)] = (uint32_t)t_; \
    if ((c & 7) == 0) { \
        int B_ = w*2 + (c>>3); \
        int sb_ = 121 + be_ - (RJ); sb_ = sb_ < 0 ? 0 : (sb_ > 254 ? 254 : sb_); \
        (SC)[bb_*16 + ((B_ & 3)<<2) + (B_>>2)] = (uint8_t)sb_; \
    } \
    bmout_[J] = bm_; \
} while (0)

    // ---- init: alpha_1[n] = inp[b,0,n] + trans[n,STAG]; exact max; MX-fp8 store ----
    float vv[4][4];
    {
        float tr[4];
        #pragma unroll
        for (int i = 0; i < 4; ++i) tr[i] = trans[(w*64 + i*16 + c)*NTAGS + STAG];
        #pragma unroll
        for (int j = 0; j < 4; ++j) {
            #pragma unroll
            for (int i = 0; i < 4; ++i)
                vv[j][i] = ep[j][i*16] + tr[i];
        }
    }
    float Mj[4];
    #pragma unroll
    for (int j = 0; j < 4; ++j) {
        float m = fmaxf(fmaxf(vv[j][0], vv[j][1]), fmaxf(vv[j][2], vv[j][3]));
        #pragma unroll
        for (int msk = 1; msk <= 8; msk <<= 1) m = fmaxf(m, __shfl_xor(m, msk, 64));
        if (c == 0) mxb[(b0 + j)*8 + w] = m;
    }
    __syncthreads();
    float G[4];
    #pragma unroll
    for (int j = 0; j < 4; ++j) {
        float m = -3.0e38f;
        #pragma unroll
        for (int k = 0; k < 8; ++k) m = fmaxf(m, mxb[(b0 + j)*8 + k]);
        Mj[j] = m;
        G[j] = m * L2E;
    }
    {
        float bmout_[4];
        uint8_t* AQ = aqb + 8192; uint8_t* SC = scb + 256;   // buffer 1 (s=1 reads cur=1)
        #pragma unroll
        for (int j = 0; j < 4; ++j) {
            float q0 = exp2f((vv[j][0] - Mj[j]) * L2E);
            float q1 = exp2f((vv[j][1] - Mj[j]) * L2E);
            float q2 = exp2f((vv[j][2] - Mj[j]) * L2E);
            float q3 = exp2f((vv[j][3] - Mj[j]) * L2E);
            QUANT_STORE(j, q0, q1, q2, q3, 0, AQ, SC);
        }
        (void)bmout_;
    }
    if (w == 0 && c == 0) { int4 z; z.x=0; z.y=0; z.z=0; z.w=0; *(int4*)&mxp[16 + g*4] = z; }

    // prologue: advance ep to row 1, prefetch raw em(s=1)
    float emn[4][4];
    #pragma unroll
    for (int j = 0; j < 4; ++j) ep[j] += NTAGS;
    #pragma unroll
    for (int j = 0; j < 4; ++j) {
        #pragma unroll
        for (int i = 0; i < 4; ++i) emn[j][i] = ep[j][i*16];
    }
    __syncthreads();

    int aoffA[8];
    #pragma unroll
    for (int kk = 0; kk < 4; ++kk) {
        aoffA[2*kk]   = c*32 + ((kk*8 + g*2)     ^ (c & 7));
        aoffA[2*kk+1] = c*32 + ((kk*8 + g*2 + 1) ^ (c & 7));
    }
    const int scoff = c*16 + g*4;

#define MFMA_K(KK) do { \
    v8i A_; \
    *(int4*)&A_       = aq4[aoffA[2*(KK)]]; \
    *(((int4*)&A_)+1) = aq4[aoffA[2*(KK)+1]]; \
    D[0] = __builtin_amdgcn_mfma_scale_f32_16x16x128_f8f6f4(A_, Bf[0*4+(KK)], D[0], 0, 2, (KK), scA, (KK), esc[0]); \
    D[1] = __builtin_amdgcn_mfma_scale_f32_16x16x128_f8f6f4(A_, Bf[1*4+(KK)], D[1], 0, 2, (KK), scA, (KK), esc[1]); \
    D[2] = __builtin_amdgcn_mfma_scale_f32_16x16x128_f8f6f4(A_, Bf[2*4+(KK)], D[2], 0, 2, (KK), scA, (KK), esc[2]); \
    D[3] = __builtin_amdgcn_mfma_scale_f32_16x16x128_f8f6f4(A_, Bf[3*4+(KK)], D[3], 0, 2, (KK), scA, (KK), esc[3]); \
} while (0)

    for (int s = 1; s < SEQ; ++s) {
        const int cur = s & 1, nxt = cur ^ 1;

        // exp factors for CURRENT step (raw em was prefetched last step, already resident)
        float emx[4][4];
        #pragma unroll
        for (int j = 0; j < 4; ++j) {
            #pragma unroll
            for (int i = 0; i < 4; ++i) emx[j][i] = exp2f(emn[j][i] * L2E);
        }
        // prefetch raw em for NEXT step (drained by this step's end-barrier)
        if (s < SEQ - 1) {
            #pragma unroll
            for (int j = 0; j < 4; ++j) ep[j] += NTAGS;
            #pragma unroll
            for (int j = 0; j < 4; ++j) {
                #pragma unroll
                for (int i = 0; i < 4; ++i) emn[j][i] = ep[j][i*16];
            }
        }

        int4 Pv = *(const int4*)&mxp[cur*16 + g*4];
        uint32_t scA = *(const uint32_t*)(scb + cur*256 + scoff);
        const int4* aq4 = (const int4*)(aqb + cur*8192);

        v4f D[4];
        #pragma unroll
        for (int i = 0; i < 4; ++i) { D[i][0]=0.f; D[i][1]=0.f; D[i][2]=0.f; D[i][3]=0.f; }
        MFMA_K(0); MFMA_K(1); MFMA_K(2); MFMA_K(3);

        if (s < SEQ - 1) {
            int Rj[4];
            #pragma unroll
            for (int j = 0; j < 4; ++j) {
                Rj[j] = ((const int*)&Pv)[j] + 8;
                G[j] += (float)Rj[j];
            }
            float bmout_[4];
            uint8_t* AQ = aqb + nxt*8192; uint8_t* SC = scb + nxt*256;
            #pragma unroll
            for (int j = 0; j < 4; ++j) {
                float v0 = D[0][j] * emx[j][0];
                float v1 = D[1][j] * emx[j][1];
                float v2 = D[2][j] * emx[j][2];
                float v3 = D[3][j] * emx[j][3];
                QUANT_STORE(j, v0, v1, v2, v3, Rj[j], AQ, SC);
            }
            if (w == 0) {
                int4 post;
                #pragma unroll
                for (int j = 0; j < 4; ++j) {
                    float bb = DPPMAX(bmout_[j], 0x140);   // 16-lane (batch) max
                    int be0 = (int)((__float_as_uint(bb) >> 23) & 255u) - 127;
                    ((int*)&post)[j] = be0 - Rj[j];
                }
                if (c == 0) *(int4*)&mxp[nxt*16 + g*4] = post;
            }
            __syncthreads();
        } else {
            // ---- final: loss_b = LN2*(G + max_x + log2 sum 2^(x - max)); emn holds raw em(511) ----
            float ts[4];
            #pragma unroll
            for (int i = 0; i < 4; ++i) ts[i] = trans[PTAG*NTAGS + w*64 + i*16 + c];
            float x[4][4];
            #pragma unroll
            for (int j = 0; j < 4; ++j) {
                #pragma unroll
                for (int i = 0; i < 4; ++i)
                    x[j][i] = __log2f(D[i][j]) + (emn[j][i] + ts[i]) * L2E;
            }
            #pragma unroll
            for (int j = 0; j < 4; ++j) {
                float m = fmaxf(fmaxf(x[j][0], x[j][1]), fmaxf(x[j][2], x[j][3]));
                #pragma unroll
                for (int msk = 1; msk <= 8; msk <<= 1) m = fmaxf(m, __shfl_xor(m, msk, 64));
                if (c == 0) mxb[(b0 + j)*8 + w] = m;
            }
            if (w == 0 && c == 0) {
                #pragma unroll
                for (int j = 0; j < 4; ++j) Gb[b0 + j] = G[j];
            }
            __syncthreads();
            #pragma unroll
            for (int j = 0; j < 4; ++j) {
                float XM = -3.0e38f;
                #pragma unroll
                for (int k = 0; k < 8; ++k) XM = fmaxf(XM, mxb[(b0 + j)*8 + k]);
                float sj = exp2f(x[j][0] - XM) + exp2f(x[j][1] - XM)
                         + exp2f(x[j][2] - XM) + exp2f(x[j][3] - XM);
                #pragma unroll
                for (int msk = 1; msk <= 8; msk <<= 1) sj += __shfl_xor(sj, msk, 64);
                if (c == 0) ssum[(b0 + j)*8 + w] = sj;
            }
            __syncthreads();
            if (tid < 16) {
                float S = 0.f, XM = -3.0e38f;
                #pragma unroll
                for (int k = 0; k < 8; ++k) { S += ssum[tid*8 + k]; XM = fmaxf(XM, mxb[tid*8 + k]); }
                part[wg*16 + tid] = LN2 * (Gb[tid] + XM + __log2f(S));
            }
        }
    }
#undef MFMA_K
#undef QUANT_STORE
}

__global__ void crf_final_k(const float* __restrict__ part, float* __restrict__ out)
{
    int t = threadIdx.x;  // 64
    float vsum = part[t] + part[t + 64];
    #pragma unroll
    for (int off = 32; off; off >>= 1) vsum += __shfl_down(vsum, off, 64);
    if (t == 0) out[0] = vsum;
}

extern "C" void kernel_launch(void* const* d_in, const int* in_sizes, int n_in,
                              void* d_out, int out_size, void* d_ws, size_t ws_size,
                              hipStream_t stream)
{
    (void)in_sizes; (void)n_in; (void)out_size; (void)ws_size;
    const float* inp   = (const float*)d_in[0];
    // d_in[1] = tags: unused (partition function only)
    const float* trans = (const float*)d_in[2];
    float* part = (float*)d_ws;

    crf_main_k<<<8, 512, 0, stream>>>(inp, trans, part);
    crf_final_k<<<1, 64, 0, stream>>>(part, (float*)d_out);
}

// Round 4
// 929.425 us; speedup vs baseline: 3.6925x; 3.6925x over previous
//
#include <hip/hip_runtime.h>
#include <stdint.h>

#define NTAGS 512
#define STAG 510
#define PTAG 511
#define SEQ 512
#define L2E 1.4426950408889634f
#define LN2 0.6931471805599453f

typedef int   v8i __attribute__((ext_vector_type(8)));
typedef float v4f __attribute__((ext_vector_type(4)));

// max with a DPP-permuted copy (ctrl must be a literal)
#define DPPMAX(X, CTRL) fmaxf((X), __int_as_float(__builtin_amdgcn_update_dpp( \
    0, __float_as_int(X), (CTRL), 0xF, 0xF, false)))
// 0xB1 = quad_perm xor1 ; 0x4E = quad_perm xor2 ; 0x141 = row_half_mirror (xor7) ; 0x140 = row_mirror (xor15)

// raw barrier: order LDS only; leave VMEM (em prefetch) in flight across it
#define STEP_SYNC() asm volatile("s_waitcnt lgkmcnt(0)\n\ts_barrier" ::: "memory")

// ws layout: E6 fp6 blocks 512*16*24B = 196608 | scales 8192 | part 512B
#define WS_SC   196608
#define WS_PART 204800

// ---------------- setup: E = exp(trans) -> MX-fp6 e2m3, k-permuted, packed 6 dwords ----
// Block (n, KB), KB = kk*4 + g. k-permutation p = (KB>>1)*64 + (idx&3)*16 + (KB&1)*8 + (idx>>2).
__global__ void crf_setup_k(const float* __restrict__ trans, uint8_t* __restrict__ ws)
{
    int t = blockIdx.x * blockDim.x + threadIdx.x;   // 8192 threads
    int n = t >> 4, KB = t & 15;
    const float* row = trans + n * NTAGS;
    int wq = KB >> 1, h = KB & 1;
    float v[32]; float mx = -3.0e38f;
    #pragma unroll
    for (int k = 0; k < 32; ++k) {
        int p = wq*64 + (k & 3)*16 + h*8 + (k >> 2);
        v[k] = row[p]; mx = fmaxf(mx, v[k]);
    }
    int e = (int)floorf(mx * L2E - 2.90689059f);     // blockmax -> (3.75, 7.5]
    int byt = e + 127; byt = byt < 0 ? 0 : (byt > 254 ? 254 : byt);
    float eeff = (float)(byt - 127);
    uint32_t out[6] = {0u,0u,0u,0u,0u,0u};
    #pragma unroll
    for (int k = 0; k < 32; ++k) {
        float q = exp2f(v[k] * L2E - eeff);          // in [0, 7.5]
        int code;
        if      (q < 2.0f) code = (int)(q * 8.0f + 0.5f);
        else if (q < 4.0f) code = 16 + (int)((q - 2.0f) * 4.0f + 0.5f);
        else               code = 24 + (int)((q - 4.0f) * 2.0f + 0.5f);
        code = code > 31 ? 31 : code;
        int bp = 6*k, d = bp >> 5, off = bp & 31;
        out[d] |= (uint32_t)code << off;
        if (off > 26) out[d+1] |= (uint32_t)code >> (32 - off);
    }
    uint32_t* E6 = (uint32_t*)ws;
    int base = (n*16 + KB) * 6;
    #pragma unroll
    for (int d = 0; d < 6; ++d) E6[base + d] = out[d];
    ws[WS_SC + n*16 + (KB & 3)*4 + (KB >> 2)] = (uint8_t)byt;
}

// ---------------- main: 8 WGs x 16 batches, 512 threads (8 waves) ----------------
__global__ __launch_bounds__(512, 2) void crf_main_k(
    const float* __restrict__ inp, const float* __restrict__ trans,
    const uint8_t* __restrict__ ws, float* __restrict__ part)
{
    __shared__ uint8_t aqb[2*8192];
    __shared__ uint8_t scb[2*256];
    __shared__ int     mxp[2*16];
    __shared__ float   mxb[16*8];
    __shared__ float   ssum[16*8];
    __shared__ float   Gb[16];

    const int tid = threadIdx.x;
    const int w = tid >> 6, l = tid & 63, c = l & 15, g = l >> 4;
    const int wg = blockIdx.x;
    const int b0 = g * 4;

    // ---- persistent B fragments: plain vector loads (low pressure -> no spill) ----
    v8i Bf[16];
    int esc[4];
    #pragma unroll
    for (int i = 0; i < 4; ++i) {
        const int n = (w*4 + i)*16 + c;
        esc[i] = *(const int*)(ws + WS_SC + n*16 + g*4);
        #pragma unroll
        for (int kk = 0; kk < 4; ++kk) {
            const uint2* p2 = (const uint2*)((const uint32_t*)ws + (n*16 + kk*4 + g)*6);
            uint2 d0 = p2[0], d1 = p2[1], d2 = p2[2];
            v8i bv;
            bv[0]=(int)d0.x; bv[1]=(int)d0.y; bv[2]=(int)d1.x;
            bv[3]=(int)d1.y; bv[4]=(int)d2.x; bv[5]=(int)d2.y;
            bv[6]=0; bv[7]=0;
            Bf[i*4 + kk] = bv;
        }
    }

    const float* ep[4];
    #pragma unroll
    for (int j = 0; j < 4; ++j)
        ep[j] = inp + (size_t)(wg*16 + b0 + j) * (SEQ*NTAGS) + w*64 + c;   // row 0

// quantize 4 values (i=0..3) of batch b0+J into AQ/SC with fold RJ.
#define QUANT_STORE(J, V0, V1, V2, V3, RJ, AQ, SC) do { \
    float bm_ = fmaxf(fmaxf(V0, V1), fmaxf(V2, V3)); \
    bm_ = DPPMAX(bm_, 0xB1); bm_ = DPPMAX(bm_, 0x4E); bm_ = DPPMAX(bm_, 0x141); \
    int be_ = (int)((__float_as_uint(bm_) >> 23) & 255u) - 127; \
    be_ = be_ < -60 ? -60 : be_; \
    float qs_ = __int_as_float((uint32_t)(133 - be_) << 23); \
    int t_ = __builtin_amdgcn_cvt_pk_fp8_f32((V0)*qs_, (V1)*qs_, 0, false); \
    t_ = __builtin_amdgcn_cvt_pk_fp8_f32((V2)*qs_, (V3)*qs_, t_, true); \
    int bb_ = b0 + (J); \
    ((uint32_t*)(AQ))[bb_*128 + (((w*4 + (c>>2)) ^ (bb_ & 7)) << 2) + (c & 3)] = (uint32_t)t_; \
    if ((c & 7) == 0) { \
        int B_ = w*2 + (c>>3); \
        int sb_ = 121 + be_ - (RJ); sb_ = sb_ < 0 ? 0 : (sb_ > 254 ? 254 : sb_); \
        (SC)[bb_*16 + ((B_ & 3)<<2) + (B_>>2)] = (uint8_t)sb_; \
    } \
    bmout_[J] = bm_; \
} while (0)

    // ---- init: alpha_1[n] = inp[b,0,n] + trans[n,STAG]; exact max; MX-fp8 store ----
    float vv[4][4];
    {
        float tr[4];
        #pragma unroll
        for (int i = 0; i < 4; ++i) tr[i] = trans[(w*64 + i*16 + c)*NTAGS + STAG];
        #pragma unroll
        for (int j = 0; j < 4; ++j) {
            #pragma unroll
            for (int i = 0; i < 4; ++i)
                vv[j][i] = ep[j][i*16] + tr[i];
        }
    }
    float Mj[4];
    #pragma unroll
    for (int j = 0; j < 4; ++j) {
        float m = fmaxf(fmaxf(vv[j][0], vv[j][1]), fmaxf(vv[j][2], vv[j][3]));
        #pragma unroll
        for (int msk = 1; msk <= 8; msk <<= 1) m = fmaxf(m, __shfl_xor(m, msk, 64));
        if (c == 0) mxb[(b0 + j)*8 + w] = m;
    }
    __syncthreads();
    float G[4];
    #pragma unroll
    for (int j = 0; j < 4; ++j) {
        float m = -3.0e38f;
        #pragma unroll
        for (int k = 0; k < 8; ++k) m = fmaxf(m, mxb[(b0 + j)*8 + k]);
        Mj[j] = m;
        G[j] = m * L2E;
    }
    {
        float bmout_[4];
        uint8_t* AQ = aqb + 8192; uint8_t* SC = scb + 256;   // buffer 1 (s=1 reads cur=1)
        #pragma unroll
        for (int j = 0; j < 4; ++j) {
            float q0 = exp2f((vv[j][0] - Mj[j]) * L2E);
            float q1 = exp2f((vv[j][1] - Mj[j]) * L2E);
            float q2 = exp2f((vv[j][2] - Mj[j]) * L2E);
            float q3 = exp2f((vv[j][3] - Mj[j]) * L2E);
            QUANT_STORE(j, q0, q1, q2, q3, 0, AQ, SC);
        }
        (void)bmout_;
    }
    if (w == 0 && c == 0) { int4 z; z.x=0; z.y=0; z.z=0; z.w=0; *(int4*)&mxp[16 + g*4] = z; }

    // prologue: advance ep to row 1, prefetch raw em(s=1)
    float emn[4][4];
    #pragma unroll
    for (int j = 0; j < 4; ++j) ep[j] += NTAGS;
    #pragma unroll
    for (int j = 0; j < 4; ++j) {
        #pragma unroll
        for (int i = 0; i < 4; ++i) emn[j][i] = ep[j][i*16];
    }
    __syncthreads();

    int aoffA[8];
    #pragma unroll
    for (int kk = 0; kk < 4; ++kk) {
        aoffA[2*kk]   = c*32 + ((kk*8 + g*2)     ^ (c & 7));
        aoffA[2*kk+1] = c*32 + ((kk*8 + g*2 + 1) ^ (c & 7));
    }
    const int scoff = c*16 + g*4;

#define MFMA_K(KK) do { \
    v8i A_; \
    *(int4*)&A_       = aq4[aoffA[2*(KK)]]; \
    *(((int4*)&A_)+1) = aq4[aoffA[2*(KK)+1]]; \
    D[0] = __builtin_amdgcn_mfma_scale_f32_16x16x128_f8f6f4(A_, Bf[0*4+(KK)], D[0], 0, 2, (KK), scA, (KK), esc[0]); \
    D[1] = __builtin_amdgcn_mfma_scale_f32_16x16x128_f8f6f4(A_, Bf[1*4+(KK)], D[1], 0, 2, (KK), scA, (KK), esc[1]); \
    D[2] = __builtin_amdgcn_mfma_scale_f32_16x16x128_f8f6f4(A_, Bf[2*4+(KK)], D[2], 0, 2, (KK), scA, (KK), esc[2]); \
    D[3] = __builtin_amdgcn_mfma_scale_f32_16x16x128_f8f6f4(A_, Bf[3*4+(KK)], D[3], 0, 2, (KK), scA, (KK), esc[3]); \
} while (0)

    for (int s = 1; s < SEQ; ++s) {
        const int cur = s & 1, nxt = cur ^ 1;

        // exp factors for CURRENT step (raw em prefetched last step, already resident)
        float emx[4][4];
        #pragma unroll
        for (int j = 0; j < 4; ++j) {
            #pragma unroll
            for (int i = 0; i < 4; ++i) emx[j][i] = exp2f(emn[j][i] * L2E);
        }
        // prefetch raw em for NEXT step (survives the raw barrier; drains at next use)
        if (s < SEQ - 1) {
            #pragma unroll
            for (int j = 0; j < 4; ++j) ep[j] += NTAGS;
            #pragma unroll
            for (int j = 0; j < 4; ++j) {
                #pragma unroll
                for (int i = 0; i < 4; ++i) emn[j][i] = ep[j][i*16];
            }
        }

        int4 Pv = *(const int4*)&mxp[cur*16 + g*4];
        uint32_t scA = *(const uint32_t*)(scb + cur*256 + scoff);
        const int4* aq4 = (const int4*)(aqb + cur*8192);

        v4f D[4];
        #pragma unroll
        for (int i = 0; i < 4; ++i) { D[i][0]=0.f; D[i][1]=0.f; D[i][2]=0.f; D[i][3]=0.f; }
        MFMA_K(0); MFMA_K(1); MFMA_K(2); MFMA_K(3);

        if (s < SEQ - 1) {
            int Rj[4];
            #pragma unroll
            for (int j = 0; j < 4; ++j) {
                Rj[j] = ((const int*)&Pv)[j] + 8;
                G[j] += (float)Rj[j];
            }
            float bmout_[4];
            uint8_t* AQ = aqb + nxt*8192; uint8_t* SC = scb + nxt*256;
            #pragma unroll
            for (int j = 0; j < 4; ++j) {
                float v0 = D[0][j] * emx[j][0];
                float v1 = D[1][j] * emx[j][1];
                float v2 = D[2][j] * emx[j][2];
                float v3 = D[3][j] * emx[j][3];
                QUANT_STORE(j, v0, v1, v2, v3, Rj[j], AQ, SC);
            }
            if (w == 0) {
                int4 post;
                #pragma unroll
                for (int j = 0; j < 4; ++j) {
                    float bb = DPPMAX(bmout_[j], 0x140);   // 16-lane (batch) max
                    int be0 = (int)((__float_as_uint(bb) >> 23) & 255u) - 127;
                    ((int*)&post)[j] = be0 - Rj[j];
                }
                if (c == 0) *(int4*)&mxp[nxt*16 + g*4] = post;
            }
            STEP_SYNC();
        } else {
            // ---- final: loss_b = LN2*(G + max_x + log2 sum 2^(x - max)); emn holds raw em(511) ----
            float ts[4];
            #pragma unroll
            for (int i = 0; i < 4; ++i) ts[i] = trans[PTAG*NTAGS + w*64 + i*16 + c];
            float x[4][4];
            #pragma unroll
            for (int j = 0; j < 4; ++j) {
                #pragma unroll
                for (int i = 0; i < 4; ++i)
                    x[j][i] = __log2f(D[i][j]) + (emn[j][i] + ts[i]) * L2E;
            }
            #pragma unroll
            for (int j = 0; j < 4; ++j) {
                float m = fmaxf(fmaxf(x[j][0], x[j][1]), fmaxf(x[j][2], x[j][3]));
                #pragma unroll
                for (int msk = 1; msk <= 8; msk <<= 1) m = fmaxf(m, __shfl_xor(m, msk, 64));
                if (c == 0) mxb[(b0 + j)*8 + w] = m;
            }
            if (w == 0 && c == 0) {
                #pragma unroll
                for (int j = 0; j < 4; ++j) Gb[b0 + j] = G[j];
            }
            __syncthreads();
            #pragma unroll
            for (int j = 0; j < 4; ++j) {
                float XM = -3.0e38f;
                #pragma unroll
                for (int k = 0; k < 8; ++k) XM = fmaxf(XM, mxb[(b0 + j)*8 + k]);
                float sj = exp2f(x[j][0] - XM) + exp2f(x[j][1] - XM)
                         + exp2f(x[j][2] - XM) + exp2f(x[j][3] - XM);
                #pragma unroll
                for (int msk = 1; msk <= 8; msk <<= 1) sj += __shfl_xor(sj, msk, 64);
                if (c == 0) ssum[(b0 + j)*8 + w] = sj;
            }
            __syncthreads();
            if (tid < 16) {
                float S = 0.f, XM = -3.0e38f;
                #pragma unroll
                for (int k = 0; k < 8; ++k) { S += ssum[tid*8 + k]; XM = fmaxf(XM, mxb[tid*8 + k]); }
                part[wg*16 + tid] = LN2 * (Gb[tid] + XM + __log2f(S));
            }
        }
    }
#undef MFMA_K
#undef QUANT_STORE
}

__global__ void crf_final_k(const float* __restrict__ part, float* __restrict__ out)
{
    int t = threadIdx.x;  // 64
    float vsum = part[t] + part[t + 64];
    #pragma unroll
    for (int off = 32; off; off >>= 1) vsum += __shfl_down(vsum, off, 64);
    if (t == 0) out[0] = vsum;
}

extern "C" void kernel_launch(void* const* d_in, const int* in_sizes, int n_in,
                              void* d_out, int out_size, void* d_ws, size_t ws_size,
                              hipStream_t stream)
{
    (void)in_sizes; (void)n_in; (void)out_size; (void)ws_size;
    const float* inp   = (const float*)d_in[0];
    // d_in[1] = tags: unused (partition function only)
    const float* trans = (const float*)d_in[2];
    uint8_t* ws = (uint8_t*)d_ws;
    float* part = (float*)(ws + WS_PART);

    crf_setup_k<<<64, 128, 0, stream>>>(trans, ws);
    crf_main_k<<<8, 512, 0, stream>>>(inp, trans, ws, part);
    crf_final_k<<<1, 64, 0, stream>>>(part, (float*)d_out);
}

// Round 5
// 921.146 us; speedup vs baseline: 3.7257x; 1.0090x over previous
//
#include <hip/hip_runtime.h>
#include <stdint.h>

#define NTAGS 512
#define STAG 510
#define PTAG 511
#define SEQ 512
#define L2E 1.4426950408889634f
#define LN2 0.6931471805599453f

typedef int   v8i __attribute__((ext_vector_type(8)));
typedef float v4f __attribute__((ext_vector_type(4)));

// max with a DPP-permuted copy (ctrl must be a literal)
#define DPPMAX(X, CTRL) fmaxf((X), __int_as_float(__builtin_amdgcn_update_dpp( \
    0, __float_as_int(X), (CTRL), 0xF, 0xF, false)))
// 0xB1 = quad_perm xor1 ; 0x4E = quad_perm xor2 ; 0x141 = row_half_mirror (xor7) ; 0x140 = row_mirror (xor15)

// raw barrier: order LDS only; leave VMEM (em prefetch) in flight across it
#define STEP_SYNC() asm volatile("s_waitcnt lgkmcnt(0)\n\ts_barrier" ::: "memory")

// ws layout: E6 fp6 blocks 512*16*24B = 196608 | scales 8192 | part 512B
#define WS_SC   196608
#define WS_PART 204800

// ---------------- setup: E = exp(trans) -> MX-fp6 e2m3, k-permuted, packed 6 dwords ----
// Block (n, KB), KB = kk*4 + g. k-permutation p = (KB>>1)*64 + (idx&3)*16 + (KB&1)*8 + (idx>>2).
__global__ void crf_setup_k(const float* __restrict__ trans, uint8_t* __restrict__ ws)
{
    int t = blockIdx.x * blockDim.x + threadIdx.x;   // 8192 threads
    int n = t >> 4, KB = t & 15;
    const float* row = trans + n * NTAGS;
    int wq = KB >> 1, h = KB & 1;
    float v[32]; float mx = -3.0e38f;
    #pragma unroll
    for (int k = 0; k < 32; ++k) {
        int p = wq*64 + (k & 3)*16 + h*8 + (k >> 2);
        v[k] = row[p]; mx = fmaxf(mx, v[k]);
    }
    int e = (int)floorf(mx * L2E - 2.90689059f);     // blockmax -> (3.75, 7.5]
    int byt = e + 127; byt = byt < 0 ? 0 : (byt > 254 ? 254 : byt);
    float eeff = (float)(byt - 127);
    uint32_t out[6] = {0u,0u,0u,0u,0u,0u};
    #pragma unroll
    for (int k = 0; k < 32; ++k) {
        float q = exp2f(v[k] * L2E - eeff);          // in [0, 7.5]
        int code;
        if      (q < 2.0f) code = (int)(q * 8.0f + 0.5f);
        else if (q < 4.0f) code = 16 + (int)((q - 2.0f) * 4.0f + 0.5f);
        else               code = 24 + (int)((q - 4.0f) * 2.0f + 0.5f);
        code = code > 31 ? 31 : code;
        int bp = 6*k, d = bp >> 5, off = bp & 31;
        out[d] |= (uint32_t)code << off;
        if (off > 26) out[d+1] |= (uint32_t)code >> (32 - off);
    }
    uint32_t* E6 = (uint32_t*)ws;
    int base = (n*16 + KB) * 6;
    #pragma unroll
    for (int d = 0; d < 6; ++d) E6[base + d] = out[d];
    ws[WS_SC + n*16 + (KB & 3)*4 + (KB >> 2)] = (uint8_t)byt;
}

// ---------------- main: 8 WGs x 16 batches, 512 threads (8 waves) ----------------
__global__ __launch_bounds__(512, 2) void crf_main_k(
    const float* __restrict__ inp, const float* __restrict__ trans,
    const uint8_t* __restrict__ ws, float* __restrict__ part)
{
    __shared__ uint8_t aqb[2*8192];
    __shared__ uint8_t scb[2*256];
    __shared__ int     mxp[2*16];
    __shared__ float   mxb[16*8];
    __shared__ float   ssum[16*8];
    __shared__ float   Gb[16];

    const int tid = threadIdx.x;
    const int w = tid >> 6, l = tid & 63, c = l & 15, g = l >> 4;
    const int wg = blockIdx.x;
    const int b0 = g * 4;

    // ---- persistent B fragments: plain vector loads ----
    v8i Bf[16];
    int esc[4];
    #pragma unroll
    for (int i = 0; i < 4; ++i) {
        const int n = (w*4 + i)*16 + c;
        esc[i] = *(const int*)(ws + WS_SC + n*16 + g*4);
        #pragma unroll
        for (int kk = 0; kk < 4; ++kk) {
            const uint2* p2 = (const uint2*)((const uint32_t*)ws + (n*16 + kk*4 + g)*6);
            uint2 d0 = p2[0], d1 = p2[1], d2 = p2[2];
            v8i bv;
            bv[0]=(int)d0.x; bv[1]=(int)d0.y; bv[2]=(int)d1.x;
            bv[3]=(int)d1.y; bv[4]=(int)d2.x; bv[5]=(int)d2.y;
            bv[6]=0; bv[7]=0;
            Bf[i*4 + kk] = bv;
        }
    }
    // Pin Bf/esc in registers: opaque to the allocator -> cannot be
    // rematerialized (sunk into the loop as per-step L2 reloads, the R4
    // failure) and must stay live. Peak pressure ~225 < 256, so no spill.
    #pragma unroll
    for (int i = 0; i < 16; ++i) asm volatile("" : "+v"(Bf[i]));
    #pragma unroll
    for (int i = 0; i < 4; ++i)  asm volatile("" : "+v"(esc[i]));

    const float* ep[4];
    #pragma unroll
    for (int j = 0; j < 4; ++j)
        ep[j] = inp + (size_t)(wg*16 + b0 + j) * (SEQ*NTAGS) + w*64 + c;   // row 0

// quantize 4 values (i=0..3) of batch b0+J into AQ/SC with fold RJ.
#define QUANT_STORE(J, V0, V1, V2, V3, RJ, AQ, SC) do { \
    float bm_ = fmaxf(fmaxf(V0, V1), fmaxf(V2, V3)); \
    bm_ = DPPMAX(bm_, 0xB1); bm_ = DPPMAX(bm_, 0x4E); bm_ = DPPMAX(bm_, 0x141); \
    int be_ = (int)((__float_as_uint(bm_) >> 23) & 255u) - 127; \
    be_ = be_ < -60 ? -60 : be_; \
    float qs_ = __int_as_float((uint32_t)(133 - be_) << 23); \
    int t_ = __builtin_amdgcn_cvt_pk_fp8_f32((V0)*qs_, (V1)*qs_, 0, false); \
    t_ = __builtin_amdgcn_cvt_pk_fp8_f32((V2)*qs_, (V3)*qs_, t_, true); \
    int bb_ = b0 + (J); \
    ((uint32_t*)(AQ))[bb_*128 + (((w*4 + (c>>2)) ^ (bb_ & 7)) << 2) + (c & 3)] = (uint32_t)t_; \
    if ((c & 7) == 0) { \
        int B_ = w*2 + (c>>3); \
        int sb_ = 121 + be_ - (RJ); sb_ = sb_ < 0 ? 0 : (sb_ > 254 ? 254 : sb_); \
        (SC)[bb_*16 + ((B_ & 3)<<2) + (B_>>2)] = (uint8_t)sb_; \
    } \
    bmout_[J] = bm_; \
} while (0)

    // ---- init: alpha_1[n] = inp[b,0,n] + trans[n,STAG]; exact max; MX-fp8 store ----
    float vv[4][4];
    {
        float tr[4];
        #pragma unroll
        for (int i = 0; i < 4; ++i) tr[i] = trans[(w*64 + i*16 + c)*NTAGS + STAG];
        #pragma unroll
        for (int j = 0; j < 4; ++j) {
            #pragma unroll
            for (int i = 0; i < 4; ++i)
                vv[j][i] = ep[j][i*16] + tr[i];
        }
    }
    float Mj[4];
    #pragma unroll
    for (int j = 0; j < 4; ++j) {
        float m = fmaxf(fmaxf(vv[j][0], vv[j][1]), fmaxf(vv[j][2], vv[j][3]));
        #pragma unroll
        for (int msk = 1; msk <= 8; msk <<= 1) m = fmaxf(m, __shfl_xor(m, msk, 64));
        if (c == 0) mxb[(b0 + j)*8 + w] = m;
    }
    __syncthreads();
    float G[4];
    #pragma unroll
    for (int j = 0; j < 4; ++j) {
        float m = -3.0e38f;
        #pragma unroll
        for (int k = 0; k < 8; ++k) m = fmaxf(m, mxb[(b0 + j)*8 + k]);
        Mj[j] = m;
        G[j] = m * L2E;
    }
    {
        float bmout_[4];
        uint8_t* AQ = aqb + 8192; uint8_t* SC = scb + 256;   // buffer 1 (s=1 reads cur=1)
        #pragma unroll
        for (int j = 0; j < 4; ++j) {
            float q0 = exp2f((vv[j][0] - Mj[j]) * L2E);
            float q1 = exp2f((vv[j][1] - Mj[j]) * L2E);
            float q2 = exp2f((vv[j][2] - Mj[j]) * L2E);
            float q3 = exp2f((vv[j][3] - Mj[j]) * L2E);
            QUANT_STORE(j, q0, q1, q2, q3, 0, AQ, SC);
        }
        (void)bmout_;
    }
    if (w == 0 && c == 0) { int4 z; z.x=0; z.y=0; z.z=0; z.w=0; *(int4*)&mxp[16 + g*4] = z; }

    // prologue: advance ep to row 1, prefetch raw em(s=1)
    float emn[4][4];
    #pragma unroll
    for (int j = 0; j < 4; ++j) ep[j] += NTAGS;
    #pragma unroll
    for (int j = 0; j < 4; ++j) {
        #pragma unroll
        for (int i = 0; i < 4; ++i) emn[j][i] = ep[j][i*16];
    }
    __syncthreads();

    int aoffA[8];
    #pragma unroll
    for (int kk = 0; kk < 4; ++kk) {
        aoffA[2*kk]   = c*32 + ((kk*8 + g*2)     ^ (c & 7));
        aoffA[2*kk+1] = c*32 + ((kk*8 + g*2 + 1) ^ (c & 7));
    }
    const int scoff = c*16 + g*4;

#define MFMA_K(KK) do { \
    v8i A_; \
    *(int4*)&A_       = aq4[aoffA[2*(KK)]]; \
    *(((int4*)&A_)+1) = aq4[aoffA[2*(KK)+1]]; \
    D[0] = __builtin_amdgcn_mfma_scale_f32_16x16x128_f8f6f4(A_, Bf[0*4+(KK)], D[0], 0, 2, (KK), scA, (KK), esc[0]); \
    D[1] = __builtin_amdgcn_mfma_scale_f32_16x16x128_f8f6f4(A_, Bf[1*4+(KK)], D[1], 0, 2, (KK), scA, (KK), esc[1]); \
    D[2] = __builtin_amdgcn_mfma_scale_f32_16x16x128_f8f6f4(A_, Bf[2*4+(KK)], D[2], 0, 2, (KK), scA, (KK), esc[2]); \
    D[3] = __builtin_amdgcn_mfma_scale_f32_16x16x128_f8f6f4(A_, Bf[3*4+(KK)], D[3], 0, 2, (KK), scA, (KK), esc[3]); \
} while (0)

    for (int s = 1; s < SEQ; ++s) {
        const int cur = s & 1, nxt = cur ^ 1;

        // exp factors for CURRENT step (raw em prefetched last step, already resident)
        float emx[4][4];
        #pragma unroll
        for (int j = 0; j < 4; ++j) {
            #pragma unroll
            for (int i = 0; i < 4; ++i) emx[j][i] = exp2f(emn[j][i] * L2E);
        }
        // prefetch raw em for NEXT step (survives the raw barrier; drains at next use)
        if (s < SEQ - 1) {
            #pragma unroll
            for (int j = 0; j < 4; ++j) ep[j] += NTAGS;
            #pragma unroll
            for (int j = 0; j < 4; ++j) {
                #pragma unroll
                for (int i = 0; i < 4; ++i) emn[j][i] = ep[j][i*16];
            }
        }

        int4 Pv = *(const int4*)&mxp[cur*16 + g*4];
        uint32_t scA = *(const uint32_t*)(scb + cur*256 + scoff);
        const int4* aq4 = (const int4*)(aqb + cur*8192);

        v4f D[4];
        #pragma unroll
        for (int i = 0; i < 4; ++i) { D[i][0]=0.f; D[i][1]=0.f; D[i][2]=0.f; D[i][3]=0.f; }
        MFMA_K(0); MFMA_K(1); MFMA_K(2); MFMA_K(3);

        if (s < SEQ - 1) {
            int Rj[4];
            #pragma unroll
            for (int j = 0; j < 4; ++j) {
                Rj[j] = ((const int*)&Pv)[j] + 8;
                G[j] += (float)Rj[j];
            }
            float bmout_[4];
            uint8_t* AQ = aqb + nxt*8192; uint8_t* SC = scb + nxt*256;
            #pragma unroll
            for (int j = 0; j < 4; ++j) {
                float v0 = D[0][j] * emx[j][0];
                float v1 = D[1][j] * emx[j][1];
                float v2 = D[2][j] * emx[j][2];
                float v3 = D[3][j] * emx[j][3];
                QUANT_STORE(j, v0, v1, v2, v3, Rj[j], AQ, SC);
            }
            if (w == 0) {
                int4 post;
                #pragma unroll
                for (int j = 0; j < 4; ++j) {
                    float bb = DPPMAX(bmout_[j], 0x140);   // 16-lane (batch) max
                    int be0 = (int)((__float_as_uint(bb) >> 23) & 255u) - 127;
                    ((int*)&post)[j] = be0 - Rj[j];
                }
                if (c == 0) *(int4*)&mxp[nxt*16 + g*4] = post;
            }
            STEP_SYNC();
        } else {
            // ---- final: loss_b = LN2*(G + max_x + log2 sum 2^(x - max)); emn holds raw em(511) ----
            float ts[4];
            #pragma unroll
            for (int i = 0; i < 4; ++i) ts[i] = trans[PTAG*NTAGS + w*64 + i*16 + c];
            float x[4][4];
            #pragma unroll
            for (int j = 0; j < 4; ++j) {
                #pragma unroll
                for (int i = 0; i < 4; ++i)
                    x[j][i] = __log2f(D[i][j]) + (emn[j][i] + ts[i]) * L2E;
            }
            #pragma unroll
            for (int j = 0; j < 4; ++j) {
                float m = fmaxf(fmaxf(x[j][0], x[j][1]), fmaxf(x[j][2], x[j][3]));
                #pragma unroll
                for (int msk = 1; msk <= 8; msk <<= 1) m = fmaxf(m, __shfl_xor(m, msk, 64));
                if (c == 0) mxb[(b0 + j)*8 + w] = m;
            }
            if (w == 0 && c == 0) {
                #pragma unroll
                for (int j = 0; j < 4; ++j) Gb[b0 + j] = G[j];
            }
            __syncthreads();
            #pragma unroll
            for (int j = 0; j < 4; ++j) {
                float XM = -3.0e38f;
                #pragma unroll
                for (int k = 0; k < 8; ++k) XM = fmaxf(XM, mxb[(b0 + j)*8 + k]);
                float sj = exp2f(x[j][0] - XM) + exp2f(x[j][1] - XM)
                         + exp2f(x[j][2] - XM) + exp2f(x[j][3] - XM);
                #pragma unroll
                for (int msk = 1; msk <= 8; msk <<= 1) sj += __shfl_xor(sj, msk, 64);
                if (c == 0) ssum[(b0 + j)*8 + w] = sj;
            }
            __syncthreads();
            if (tid < 16) {
                float S = 0.f, XM = -3.0e38f;
                #pragma unroll
                for (int k = 0; k < 8; ++k) { S += ssum[tid*8 + k]; XM = fmaxf(XM, mxb[tid*8 + k]); }
                part[wg*16 + tid] = LN2 * (Gb[tid] + XM + __log2f(S));
            }
        }
    }
#undef MFMA_K
#undef QUANT_STORE
}

__global__ void crf_final_k(const float* __restrict__ part, float* __restrict__ out)
{
    int t = threadIdx.x;  // 64
    float vsum = part[t] + part[t + 64];
    #pragma unroll
    for (int off = 32; off; off >>= 1) vsum += __shfl_down(vsum, off, 64);
    if (t == 0) out[0] = vsum;
}

extern "C" void kernel_launch(void* const* d_in, const int* in_sizes, int n_in,
                              void* d_out, int out_size, void* d_ws, size_t ws_size,
                              hipStream_t stream)
{
    (void)in_sizes; (void)n_in; (void)out_size; (void)ws_size;
    const float* inp   = (const float*)d_in[0];
    // d_in[1] = tags: unused (partition function only)
    const float* trans = (const float*)d_in[2];
    uint8_t* ws = (uint8_t*)d_ws;
    float* part = (float*)(ws + WS_PART);

    crf_setup_k<<<64, 128, 0, stream>>>(trans, ws);
    crf_main_k<<<8, 512, 0, stream>>>(inp, trans, ws, part);
    crf_final_k<<<1, 64, 0, stream>>>(part, (float*)d_out);
}

// Round 6
// 790.865 us; speedup vs baseline: 4.3395x; 1.1647x over previous
//
#include <hip/hip_runtime.h>
#include <stdint.h>

#define NTAGS 512
#define STAG 510
#define PTAG 511
#define SEQ 512
#define L2E 1.4426950408889634f
#define LN2 0.6931471805599453f

typedef int   v8i __attribute__((ext_vector_type(8)));
typedef float v4f __attribute__((ext_vector_type(4)));

// fast 2^x: raw v_exp_f32 (OCML exp2f is a ~25-instr libcall -- the R5 VALU flood)
__device__ __forceinline__ float fexp2(float x) {
#if __has_builtin(__builtin_amdgcn_exp2f)
    return __builtin_amdgcn_exp2f(x);
#else
    float r; asm("v_exp_f32 %0, %1\n\ts_nop 1" : "=v"(r) : "v"(x)); return r;
#endif
}

// max with a DPP-permuted copy (ctrl must be a literal)
#define DPPMAX(X, CTRL) fmaxf((X), __int_as_float(__builtin_amdgcn_update_dpp( \
    0, __float_as_int(X), (CTRL), 0xF, 0xF, false)))
// 0xB1 = quad_perm xor1 ; 0x4E = quad_perm xor2 ; 0x141 = row_half_mirror (xor7) ; 0x140 = row_mirror (xor15)

// raw barrier: order LDS only; leave VMEM (em prefetch) in flight across it
#define STEP_SYNC() asm volatile("s_waitcnt lgkmcnt(0)\n\ts_barrier" ::: "memory")

// ws layout: E6 fp6 blocks 512*16*24B = 196608 | scales 8192 | part 512B
#define WS_SC   196608
#define WS_PART 204800

// ---------------- setup: E = exp(trans) -> MX-fp6 e2m3, k-permuted, packed 6 dwords ----
// Block (n, KB), KB = kk*4 + g. k-permutation p = (KB>>1)*64 + (idx&3)*16 + (KB&1)*8 + (idx>>2).
__global__ void crf_setup_k(const float* __restrict__ trans, uint8_t* __restrict__ ws)
{
    int t = blockIdx.x * blockDim.x + threadIdx.x;   // 8192 threads
    int n = t >> 4, KB = t & 15;
    const float* row = trans + n * NTAGS;
    int wq = KB >> 1, h = KB & 1;
    float v[32]; float mx = -3.0e38f;
    #pragma unroll
    for (int k = 0; k < 32; ++k) {
        int p = wq*64 + (k & 3)*16 + h*8 + (k >> 2);
        v[k] = row[p]; mx = fmaxf(mx, v[k]);
    }
    int e = (int)floorf(mx * L2E - 2.90689059f);     // blockmax -> (3.75, 7.5]
    int byt = e + 127; byt = byt < 0 ? 0 : (byt > 254 ? 254 : byt);
    float eeff = (float)(byt - 127);
    uint32_t out[6] = {0u,0u,0u,0u,0u,0u};
    #pragma unroll
    for (int k = 0; k < 32; ++k) {
        float q = exp2f(v[k] * L2E - eeff);          // in [0, 7.5]
        int code;
        if      (q < 2.0f) code = (int)(q * 8.0f + 0.5f);
        else if (q < 4.0f) code = 16 + (int)((q - 2.0f) * 4.0f + 0.5f);
        else               code = 24 + (int)((q - 4.0f) * 2.0f + 0.5f);
        code = code > 31 ? 31 : code;
        int bp = 6*k, d = bp >> 5, off = bp & 31;
        out[d] |= (uint32_t)code << off;
        if (off > 26) out[d+1] |= (uint32_t)code >> (32 - off);
    }
    uint32_t* E6 = (uint32_t*)ws;
    int base = (n*16 + KB) * 6;
    #pragma unroll
    for (int d = 0; d < 6; ++d) E6[base + d] = out[d];
    ws[WS_SC + n*16 + (KB & 3)*4 + (KB >> 2)] = (uint8_t)byt;
}

// ---------------- main: 8 WGs x 16 batches, 512 threads (8 waves) ----------------
__global__ __launch_bounds__(512, 2) void crf_main_k(
    const float* __restrict__ inp, const float* __restrict__ trans,
    const uint8_t* __restrict__ ws, float* __restrict__ part)
{
    __shared__ uint8_t aqb[2*8192];
    __shared__ uint8_t scb[2*256];
    __shared__ int     mxp[2*16];
    __shared__ float   mxb[16*8];
    __shared__ float   ssum[16*8];
    __shared__ float   Gb[16];

    const int tid = threadIdx.x;
    const int w = tid >> 6, l = tid & 63, c = l & 15, g = l >> 4;
    const int wg = blockIdx.x;
    const int b0 = g * 4;

    // ---- persistent B fragments: plain vector loads ----
    v8i Bf[16];
    int esc[4];
    #pragma unroll
    for (int i = 0; i < 4; ++i) {
        const int n = (w*4 + i)*16 + c;
        esc[i] = *(const int*)(ws + WS_SC + n*16 + g*4);
        #pragma unroll
        for (int kk = 0; kk < 4; ++kk) {
            const uint2* p2 = (const uint2*)((const uint32_t*)ws + (n*16 + kk*4 + g)*6);
            uint2 d0 = p2[0], d1 = p2[1], d2 = p2[2];
            v8i bv;
            bv[0]=(int)d0.x; bv[1]=(int)d0.y; bv[2]=(int)d1.x;
            bv[3]=(int)d1.y; bv[4]=(int)d2.x; bv[5]=(int)d2.y;
            bv[6]=0; bv[7]=0;
            Bf[i*4 + kk] = bv;
        }
    }
    // keep Bf/esc pinned live across the loop (R3 spill / remat guard)
    #pragma unroll
    for (int i = 0; i < 16; ++i) asm volatile("" : "+v"(Bf[i]));
    #pragma unroll
    for (int i = 0; i < 4; ++i)  asm volatile("" : "+v"(esc[i]));

    const float* ep[4];
    #pragma unroll
    for (int j = 0; j < 4; ++j)
        ep[j] = inp + (size_t)(wg*16 + b0 + j) * (SEQ*NTAGS) + w*64 + c;   // row 0

    // hoisted quant-store indices (loop-invariant; only buffer parity alternates)
    int aqoff[4], scoffw[4];
    #pragma unroll
    for (int j = 0; j < 4; ++j) {
        int bb = b0 + j;
        aqoff[j] = bb*128 + (((w*4 + (c>>2)) ^ (bb & 7)) << 2) + (c & 3);
        int B_ = w*2 + (c>>3);
        scoffw[j] = bb*16 + ((B_ & 3)<<2) + (B_>>2);
    }

// quantize 4 values (i=0..3) of batch b0+J into AQ/SC with fold RJ.
#define QUANT_STORE(J, V0, V1, V2, V3, RJ, AQ, SC) do { \
    float bm_ = fmaxf(fmaxf(V0, V1), fmaxf(V2, V3)); \
    bm_ = DPPMAX(bm_, 0xB1); bm_ = DPPMAX(bm_, 0x4E); bm_ = DPPMAX(bm_, 0x141); \
    int be_ = (int)((__float_as_uint(bm_) >> 23) & 255u) - 127; \
    be_ = be_ < -60 ? -60 : be_; \
    float qs_ = __int_as_float((uint32_t)(133 - be_) << 23); \
    int t_ = __builtin_amdgcn_cvt_pk_fp8_f32((V0)*qs_, (V1)*qs_, 0, false); \
    t_ = __builtin_amdgcn_cvt_pk_fp8_f32((V2)*qs_, (V3)*qs_, t_, true); \
    ((uint32_t*)(AQ))[aqoff[J]] = (uint32_t)t_; \
    if ((c & 7) == 0) { \
        int sb_ = 121 + be_ - (RJ); sb_ = sb_ < 0 ? 0 : (sb_ > 254 ? 254 : sb_); \
        (SC)[scoffw[J]] = (uint8_t)sb_; \
    } \
    bmout_[J] = bm_; \
} while (0)

    // ---- init: alpha_1[n] = inp[b,0,n] + trans[n,STAG]; exact max; MX-fp8 store ----
    float vv[4][4];
    {
        float tr[4];
        #pragma unroll
        for (int i = 0; i < 4; ++i) tr[i] = trans[(w*64 + i*16 + c)*NTAGS + STAG];
        #pragma unroll
        for (int j = 0; j < 4; ++j) {
            #pragma unroll
            for (int i = 0; i < 4; ++i)
                vv[j][i] = ep[j][i*16] + tr[i];
        }
    }
    float Mj[4];
    #pragma unroll
    for (int j = 0; j < 4; ++j) {
        float m = fmaxf(fmaxf(vv[j][0], vv[j][1]), fmaxf(vv[j][2], vv[j][3]));
        #pragma unroll
        for (int msk = 1; msk <= 8; msk <<= 1) m = fmaxf(m, __shfl_xor(m, msk, 64));
        if (c == 0) mxb[(b0 + j)*8 + w] = m;
    }
    __syncthreads();
    float G[4];
    #pragma unroll
    for (int j = 0; j < 4; ++j) {
        float m = -3.0e38f;
        #pragma unroll
        for (int k = 0; k < 8; ++k) m = fmaxf(m, mxb[(b0 + j)*8 + k]);
        Mj[j] = m;
        G[j] = m * L2E;
    }
    {
        float bmout_[4];
        uint8_t* AQ = aqb + 8192; uint8_t* SC = scb + 256;   // buffer 1 (s=1 reads cur=1)
        #pragma unroll
        for (int j = 0; j < 4; ++j) {
            float q0 = fexp2((vv[j][0] - Mj[j]) * L2E);
            float q1 = fexp2((vv[j][1] - Mj[j]) * L2E);
            float q2 = fexp2((vv[j][2] - Mj[j]) * L2E);
            float q3 = fexp2((vv[j][3] - Mj[j]) * L2E);
            QUANT_STORE(j, q0, q1, q2, q3, 0, AQ, SC);
        }
        (void)bmout_;
    }
    if (w == 0 && c == 0) { int4 z; z.x=0; z.y=0; z.z=0; z.w=0; *(int4*)&mxp[16 + g*4] = z; }

    // prologue: advance ep to row 1, prefetch raw em(s=1)
    float emn[4][4];
    #pragma unroll
    for (int j = 0; j < 4; ++j) ep[j] += NTAGS;
    #pragma unroll
    for (int j = 0; j < 4; ++j) {
        #pragma unroll
        for (int i = 0; i < 4; ++i) emn[j][i] = ep[j][i*16];
    }
    __syncthreads();

    int aoffA[8];
    #pragma unroll
    for (int kk = 0; kk < 4; ++kk) {
        aoffA[2*kk]   = c*32 + ((kk*8 + g*2)     ^ (c & 7));
        aoffA[2*kk+1] = c*32 + ((kk*8 + g*2 + 1) ^ (c & 7));
    }
    const int scoff = c*16 + g*4;

#define MFMA_K(KK) do { \
    v8i A_; \
    *(int4*)&A_       = aq4[aoffA[2*(KK)]]; \
    *(((int4*)&A_)+1) = aq4[aoffA[2*(KK)+1]]; \
    D[0] = __builtin_amdgcn_mfma_scale_f32_16x16x128_f8f6f4(A_, Bf[0*4+(KK)], D[0], 0, 2, (KK), scA, (KK), esc[0]); \
    D[1] = __builtin_amdgcn_mfma_scale_f32_16x16x128_f8f6f4(A_, Bf[1*4+(KK)], D[1], 0, 2, (KK), scA, (KK), esc[1]); \
    D[2] = __builtin_amdgcn_mfma_scale_f32_16x16x128_f8f6f4(A_, Bf[2*4+(KK)], D[2], 0, 2, (KK), scA, (KK), esc[2]); \
    D[3] = __builtin_amdgcn_mfma_scale_f32_16x16x128_f8f6f4(A_, Bf[3*4+(KK)], D[3], 0, 2, (KK), scA, (KK), esc[3]); \
} while (0)

    for (int s = 1; s < SEQ; ++s) {
        const int cur = s & 1, nxt = cur ^ 1;

        // exp factors for CURRENT step (raw em prefetched last step, already resident)
        float emx[4][4];
        #pragma unroll
        for (int j = 0; j < 4; ++j) {
            #pragma unroll
            for (int i = 0; i < 4; ++i) emx[j][i] = fexp2(emn[j][i] * L2E);
        }
        // prefetch raw em for NEXT step (survives the raw barrier; drains at next use)
        if (s < SEQ - 1) {
            #pragma unroll
            for (int j = 0; j < 4; ++j) ep[j] += NTAGS;
            #pragma unroll
            for (int j = 0; j < 4; ++j) {
                #pragma unroll
                for (int i = 0; i < 4; ++i) emn[j][i] = ep[j][i*16];
            }
        }

        int4 Pv = *(const int4*)&mxp[cur*16 + g*4];
        uint32_t scA = *(const uint32_t*)(scb + cur*256 + scoff);
        const int4* aq4 = (const int4*)(aqb + cur*8192);

        v4f D[4];
        #pragma unroll
        for (int i = 0; i < 4; ++i) { D[i][0]=0.f; D[i][1]=0.f; D[i][2]=0.f; D[i][3]=0.f; }
        __builtin_amdgcn_s_setprio(1);
        MFMA_K(0); MFMA_K(1); MFMA_K(2); MFMA_K(3);
        __builtin_amdgcn_s_setprio(0);

        if (s < SEQ - 1) {
            int Rj[4];
            #pragma unroll
            for (int j = 0; j < 4; ++j) {
                Rj[j] = ((const int*)&Pv)[j] + 8;
                G[j] += (float)Rj[j];
            }
            float bmout_[4];
            uint8_t* AQ = aqb + nxt*8192; uint8_t* SC = scb + nxt*256;
            #pragma unroll
            for (int j = 0; j < 4; ++j) {
                float v0 = D[0][j] * emx[j][0];
                float v1 = D[1][j] * emx[j][1];
                float v2 = D[2][j] * emx[j][2];
                float v3 = D[3][j] * emx[j][3];
                QUANT_STORE(j, v0, v1, v2, v3, Rj[j], AQ, SC);
            }
            if (w == 0) {
                int4 post;
                #pragma unroll
                for (int j = 0; j < 4; ++j) {
                    float bb = DPPMAX(bmout_[j], 0x140);   // 16-lane (batch) max
                    int be0 = (int)((__float_as_uint(bb) >> 23) & 255u) - 127;
                    ((int*)&post)[j] = be0 - Rj[j];
                }
                if (c == 0) *(int4*)&mxp[nxt*16 + g*4] = post;
            }
            STEP_SYNC();
        } else {
            // ---- final: loss_b = LN2*(G + max_x + log2 sum 2^(x - max)); emn holds raw em(511) ----
            float ts[4];
            #pragma unroll
            for (int i = 0; i < 4; ++i) ts[i] = trans[PTAG*NTAGS + w*64 + i*16 + c];
            float x[4][4];
            #pragma unroll
            for (int j = 0; j < 4; ++j) {
                #pragma unroll
                for (int i = 0; i < 4; ++i)
                    x[j][i] = __log2f(D[i][j]) + (emn[j][i] + ts[i]) * L2E;
            }
            #pragma unroll
            for (int j = 0; j < 4; ++j) {
                float m = fmaxf(fmaxf(x[j][0], x[j][1]), fmaxf(x[j][2], x[j][3]));
                #pragma unroll
                for (int msk = 1; msk <= 8; msk <<= 1) m = fmaxf(m, __shfl_xor(m, msk, 64));
                if (c == 0) mxb[(b0 + j)*8 + w] = m;
            }
            if (w == 0 && c == 0) {
                #pragma unroll
                for (int j = 0; j < 4; ++j) Gb[b0 + j] = G[j];
            }
            __syncthreads();
            #pragma unroll
            for (int j = 0; j < 4; ++j) {
                float XM = -3.0e38f;
                #pragma unroll
                for (int k = 0; k < 8; ++k) XM = fmaxf(XM, mxb[(b0 + j)*8 + k]);
                float sj = fexp2(x[j][0] - XM) + fexp2(x[j][1] - XM)
                         + fexp2(x[j][2] - XM) + fexp2(x[j][3] - XM);
                #pragma unroll
                for (int msk = 1; msk <= 8; msk <<= 1) sj += __shfl_xor(sj, msk, 64);
                if (c == 0) ssum[(b0 + j)*8 + w] = sj;
            }
            __syncthreads();
            if (tid < 16) {
                float S = 0.f, XM = -3.0e38f;
                #pragma unroll
                for (int k = 0; k < 8; ++k) { S += ssum[tid*8 + k]; XM = fmaxf(XM, mxb[tid*8 + k]); }
                part[wg*16 + tid] = LN2 * (Gb[tid] + XM + __log2f(S));
            }
        }
    }
#undef MFMA_K
#undef QUANT_STORE
}

__global__ void crf_final_k(const float* __restrict__ part, float* __restrict__ out)
{
    int t = threadIdx.x;  // 64
    float vsum = part[t] + part[t + 64];
    #pragma unroll
    for (int off = 32; off; off >>= 1) vsum += __shfl_down(vsum, off, 64);
    if (t == 0) out[0] = vsum;
}

extern "C" void kernel_launch(void* const* d_in, const int* in_sizes, int n_in,
                              void* d_out, int out_size, void* d_ws, size_t ws_size,
                              hipStream_t stream)
{
    (void)in_sizes; (void)n_in; (void)out_size; (void)ws_size;
    const float* inp   = (const float*)d_in[0];
    // d_in[1] = tags: unused (partition function only)
    const float* trans = (const float*)d_in[2];
    uint8_t* ws = (uint8_t*)d_ws;
    float* part = (float*)(ws + WS_PART);

    crf_setup_k<<<64, 128, 0, stream>>>(trans, ws);
    crf_main_k<<<8, 512, 0, stream>>>(inp, trans, ws, part);
    crf_final_k<<<1, 64, 0, stream>>>(part, (float*)d_out);
}

// Round 7
// 646.448 us; speedup vs baseline: 5.3089x; 1.2234x over previous
//
#include <hip/hip_runtime.h>
#include <stdint.h>

#define NTAGS 512
#define STAG 510
#define PTAG 511
#define SEQ 512
#define L2E 1.4426950408889634f
#define LN2 0.6931471805599453f
#define MARGIN 13

typedef int   v8i __attribute__((ext_vector_type(8)));
typedef float v4f __attribute__((ext_vector_type(4)));

// fast 2^x: raw v_exp_f32 (OCML exp2f is a ~25-instr libcall)
__device__ __forceinline__ float fexp2(float x) {
#if __has_builtin(__builtin_amdgcn_exp2f)
    return __builtin_amdgcn_exp2f(x);
#else
    float r; asm("v_exp_f32 %0, %1\n\ts_nop 1" : "=v"(r) : "v"(x)); return r;
#endif
}

// max with a DPP-permuted copy (ctrl must be a literal)
#define DPPMAX(X, CTRL) fmaxf((X), __int_as_float(__builtin_amdgcn_update_dpp( \
    0, __float_as_int(X), (CTRL), 0xF, 0xF, false)))
// 0xB1 = quad_perm xor1 ; 0x4E = quad_perm xor2 ; 0x141 = row_half_mirror (xor7) ; 0x140 = row_mirror (xor15)

// raw barrier: order LDS only; leave VMEM (em prefetch) in flight across it
#define STEP_SYNC() asm volatile("s_waitcnt lgkmcnt(0)\n\ts_barrier" ::: "memory")

// ws layout: E6 fp6 blocks 512*16*24B = 196608 | scales 8192 | part 512B
#define WS_SC   196608
#define WS_PART 204800

// ---------------- setup: E = exp(trans) -> MX-fp6 e2m3, k-permuted, packed 6 dwords ----
// Block (n, KB), KB = kk*4 + g. k-permutation p = (KB>>1)*64 + (idx&3)*16 + (KB&1)*8 + (idx>>2).
__global__ void crf_setup_k(const float* __restrict__ trans, uint8_t* __restrict__ ws)
{
    int t = blockIdx.x * blockDim.x + threadIdx.x;   // 8192 threads
    int n = t >> 4, KB = t & 15;
    const float* row = trans + n * NTAGS;
    int wq = KB >> 1, h = KB & 1;
    float v[32]; float mx = -3.0e38f;
    #pragma unroll
    for (int k = 0; k < 32; ++k) {
        int p = wq*64 + (k & 3)*16 + h*8 + (k >> 2);
        v[k] = row[p]; mx = fmaxf(mx, v[k]);
    }
    int e = (int)floorf(mx * L2E - 2.90689059f);     // blockmax -> (3.75, 7.5]
    int byt = e + 127; byt = byt < 0 ? 0 : (byt > 254 ? 254 : byt);
    float eeff = (float)(byt - 127);
    uint32_t out[6] = {0u,0u,0u,0u,0u,0u};
    #pragma unroll
    for (int k = 0; k < 32; ++k) {
        float q = exp2f(v[k] * L2E - eeff);          // in [0, 7.5]
        int code;
        if      (q < 2.0f) code = (int)(q * 8.0f + 0.5f);
        else if (q < 4.0f) code = 16 + (int)((q - 2.0f) * 4.0f + 0.5f);
        else               code = 24 + (int)((q - 4.0f) * 2.0f + 0.5f);
        code = code > 31 ? 31 : code;
        int bp = 6*k, d = bp >> 5, off = bp & 31;
        out[d] |= (uint32_t)code << off;
        if (off > 26) out[d+1] |= (uint32_t)code >> (32 - off);
    }
    uint32_t* E6 = (uint32_t*)ws;
    int base = (n*16 + KB) * 6;
    #pragma unroll
    for (int d = 0; d < 6; ++d) E6[base + d] = out[d];
    ws[WS_SC + n*16 + (KB & 3)*4 + (KB >> 2)] = (uint8_t)byt;
}

// ---------------- main: 8 WGs x 16 batches, 512 threads (8 waves) ----------------
__global__ __launch_bounds__(512, 2) void crf_main_k(
    const float* __restrict__ inp, const float* __restrict__ trans,
    const uint8_t* __restrict__ ws, float* __restrict__ part)
{
    __shared__ uint8_t aqb[2*8192];
    __shared__ int     mxp[2*16];
    __shared__ float   mxb[16*8];
    __shared__ float   ssum[16*8];
    __shared__ float   Gb[16];

    const int tid = threadIdx.x;
    const int w = tid >> 6, l = tid & 63, c = l & 15, g = l >> 4;
    const int wg = blockIdx.x;
    const int b0 = g * 4;
    const int SCA = 0x78787878;   // constant A-scale: e8m0 120 = 2^-7, all blocks

    // ---- persistent B fragments: plain vector loads ----
    v8i Bf[16];
    int esc[4];
    #pragma unroll
    for (int i = 0; i < 4; ++i) {
        const int n = (w*4 + i)*16 + c;
        esc[i] = *(const int*)(ws + WS_SC + n*16 + g*4);
        #pragma unroll
        for (int kk = 0; kk < 4; ++kk) {
            const uint2* p2 = (const uint2*)((const uint32_t*)ws + (n*16 + kk*4 + g)*6);
            uint2 d0 = p2[0], d1 = p2[1], d2 = p2[2];
            v8i bv;
            bv[0]=(int)d0.x; bv[1]=(int)d0.y; bv[2]=(int)d1.x;
            bv[3]=(int)d1.y; bv[4]=(int)d2.x; bv[5]=(int)d2.y;
            bv[6]=0; bv[7]=0;
            Bf[i*4 + kk] = bv;
        }
    }
    // keep Bf/esc pinned live across the loop (R3 spill / remat guard)
    #pragma unroll
    for (int i = 0; i < 16; ++i) asm volatile("" : "+v"(Bf[i]));
    #pragma unroll
    for (int i = 0; i < 4; ++i)  asm volatile("" : "+v"(esc[i]));

    const float* ep[4];
    #pragma unroll
    for (int j = 0; j < 4; ++j)
        ep[j] = inp + (size_t)(wg*16 + b0 + j) * (SEQ*NTAGS) + w*64 + c;   // row 0

    // hoisted quant-store indices (loop-invariant; only buffer parity alternates)
    int aqoff[4];
    #pragma unroll
    for (int j = 0; j < 4; ++j) {
        int bb = b0 + j;
        aqoff[j] = bb*128 + (((w*4 + (c>>2)) ^ (bb & 7)) << 2) + (c & 3);
    }

    // ---- init: alpha_1[n] = inp[b,0,n] + trans[n,STAG]; exact max; fp8 store (fold 0) ----
    float vv[4][4];
    {
        float tr[4];
        #pragma unroll
        for (int i = 0; i < 4; ++i) tr[i] = trans[(w*64 + i*16 + c)*NTAGS + STAG];
        #pragma unroll
        for (int j = 0; j < 4; ++j) {
            #pragma unroll
            for (int i = 0; i < 4; ++i)
                vv[j][i] = ep[j][i*16] + tr[i];
        }
    }
    float Mj[4];
    #pragma unroll
    for (int j = 0; j < 4; ++j) {
        float m = fmaxf(fmaxf(vv[j][0], vv[j][1]), fmaxf(vv[j][2], vv[j][3]));
        #pragma unroll
        for (int msk = 1; msk <= 8; msk <<= 1) m = fmaxf(m, __shfl_xor(m, msk, 64));
        if (c == 0) mxb[(b0 + j)*8 + w] = m;
    }
    __syncthreads();
    float G[4];
    #pragma unroll
    for (int j = 0; j < 4; ++j) {
        float m = -3.0e38f;
        #pragma unroll
        for (int k = 0; k < 8; ++k) m = fmaxf(m, mxb[(b0 + j)*8 + k]);
        Mj[j] = m;
        G[j] = m * L2E;
    }
    {
        uint32_t* AQ = (uint32_t*)(aqb + 8192);   // buffer 1 (s=1 reads cur=1)
        #pragma unroll
        for (int j = 0; j < 4; ++j) {
            float q0 = fexp2((vv[j][0] - Mj[j]) * L2E + 7.0f);
            float q1 = fexp2((vv[j][1] - Mj[j]) * L2E + 7.0f);
            float q2 = fexp2((vv[j][2] - Mj[j]) * L2E + 7.0f);
            float q3 = fexp2((vv[j][3] - Mj[j]) * L2E + 7.0f);
            int t_ = __builtin_amdgcn_cvt_pk_fp8_f32(q0, q1, 0, false);
            t_ = __builtin_amdgcn_cvt_pk_fp8_f32(q2, q3, t_, true);
            AQ[aqoff[j]] = (uint32_t)t_;
        }
    }
    if (w == 0 && c == 0) { int4 z; z.x=0; z.y=0; z.z=0; z.w=0; *(int4*)&mxp[16 + g*4] = z; }

    // prologue: advance ep to row 1, prefetch raw em(s=1)
    float emn[4][4];
    #pragma unroll
    for (int j = 0; j < 4; ++j) ep[j] += NTAGS;
    #pragma unroll
    for (int j = 0; j < 4; ++j) {
        #pragma unroll
        for (int i = 0; i < 4; ++i) emn[j][i] = ep[j][i*16];
    }
    __syncthreads();

    int aoffA[8];
    #pragma unroll
    for (int kk = 0; kk < 4; ++kk) {
        aoffA[2*kk]   = c*32 + ((kk*8 + g*2)     ^ (c & 7));
        aoffA[2*kk+1] = c*32 + ((kk*8 + g*2 + 1) ^ (c & 7));
    }

#define MFMA_K(KK) do { \
    v8i A_; \
    *(int4*)&A_       = aq4[aoffA[2*(KK)]]; \
    *(((int4*)&A_)+1) = aq4[aoffA[2*(KK)+1]]; \
    D[0] = __builtin_amdgcn_mfma_scale_f32_16x16x128_f8f6f4(A_, Bf[0*4+(KK)], D[0], 0, 2, (KK), SCA, (KK), esc[0]); \
    D[1] = __builtin_amdgcn_mfma_scale_f32_16x16x128_f8f6f4(A_, Bf[1*4+(KK)], D[1], 0, 2, (KK), SCA, (KK), esc[1]); \
    D[2] = __builtin_amdgcn_mfma_scale_f32_16x16x128_f8f6f4(A_, Bf[2*4+(KK)], D[2], 0, 2, (KK), SCA, (KK), esc[2]); \
    D[3] = __builtin_amdgcn_mfma_scale_f32_16x16x128_f8f6f4(A_, Bf[3*4+(KK)], D[3], 0, 2, (KK), SCA, (KK), esc[3]); \
} while (0)

    for (int s = 1; s < SEQ; ++s) {
        const int cur = s & 1, nxt = cur ^ 1;

        // stale per-batch fold: Rj = posted-max + MARGIN; dm folds 2^(7-Rj) into emission
        int4 Pv = *(const int4*)&mxp[cur*16 + g*4];
        int Rj[4]; float dmj[4];
        #pragma unroll
        for (int j = 0; j < 4; ++j) {
            Rj[j] = ((const int*)&Pv)[j] + MARGIN;
            dmj[j] = (float)(7 - Rj[j]);
        }

        // folded emission factors (raw em prefetched last step, already resident)
        float emx[4][4];
        #pragma unroll
        for (int j = 0; j < 4; ++j) {
            #pragma unroll
            for (int i = 0; i < 4; ++i)
                emx[j][i] = fexp2(fmaf(emn[j][i], L2E, dmj[j]));
        }
        // prefetch raw em for NEXT step (survives the raw barrier; drains at next use)
        if (s < SEQ - 1) {
            #pragma unroll
            for (int j = 0; j < 4; ++j) ep[j] += NTAGS;
            #pragma unroll
            for (int j = 0; j < 4; ++j) {
                #pragma unroll
                for (int i = 0; i < 4; ++i) emn[j][i] = ep[j][i*16];
            }
        }

        const int4* aq4 = (const int4*)(aqb + cur*8192);

        v4f D[4];
        #pragma unroll
        for (int i = 0; i < 4; ++i) { D[i][0]=0.f; D[i][1]=0.f; D[i][2]=0.f; D[i][3]=0.f; }
        __builtin_amdgcn_s_setprio(1);
        MFMA_K(0); MFMA_K(1); MFMA_K(2); MFMA_K(3);
        __builtin_amdgcn_s_setprio(0);

        if (s < SEQ - 1) {
            #pragma unroll
            for (int j = 0; j < 4; ++j) G[j] += (float)Rj[j];

            // quantize: vq already carries the 2^(7-Rj) fold; constant A-scale
            float vq[4][4];
            #pragma unroll
            for (int j = 0; j < 4; ++j) {
                #pragma unroll
                for (int i = 0; i < 4; ++i)
                    vq[j][i] = fminf(D[i][j] * emx[j][i], 448.0f);
            }
            uint32_t* AQ = (uint32_t*)(aqb + nxt*8192);
            #pragma unroll
            for (int j = 0; j < 4; ++j) {
                int t_ = __builtin_amdgcn_cvt_pk_fp8_f32(vq[j][0], vq[j][1], 0, false);
                t_ = __builtin_amdgcn_cvt_pk_fp8_f32(vq[j][2], vq[j][3], t_, true);
                AQ[aqoff[j]] = (uint32_t)t_;
            }
            if (w == 0) {   // wave-uniform: stale-max post only on wave 0 (64-n sample)
                int4 post;
                #pragma unroll
                for (int j = 0; j < 4; ++j) {
                    float bm = fmaxf(fmaxf(vq[j][0], vq[j][1]), fmaxf(vq[j][2], vq[j][3]));
                    bm = DPPMAX(bm, 0xB1); bm = DPPMAX(bm, 0x4E);
                    bm = DPPMAX(bm, 0x141); bm = DPPMAX(bm, 0x140);
                    int be = (int)((__float_as_uint(bm) >> 23) & 255u) - 127;
                    be = be < -30 ? -30 : be;
                    ((int*)&post)[j] = be - 7;   // == exp(unfolded v-max) - Rj
                }
                if (c == 0) *(int4*)&mxp[nxt*16 + g*4] = post;
            }
            STEP_SYNC();
        } else {
            // ---- final: loss_b = LN2*(G + max_x + log2 sum 2^(x - max)); emn holds raw em(511) ----
            float ts[4];
            #pragma unroll
            for (int i = 0; i < 4; ++i) ts[i] = trans[PTAG*NTAGS + w*64 + i*16 + c];
            float x[4][4];
            #pragma unroll
            for (int j = 0; j < 4; ++j) {
                #pragma unroll
                for (int i = 0; i < 4; ++i)
                    x[j][i] = __log2f(D[i][j]) + (emn[j][i] + ts[i]) * L2E;
            }
            #pragma unroll
            for (int j = 0; j < 4; ++j) {
                float m = fmaxf(fmaxf(x[j][0], x[j][1]), fmaxf(x[j][2], x[j][3]));
                #pragma unroll
                for (int msk = 1; msk <= 8; msk <<= 1) m = fmaxf(m, __shfl_xor(m, msk, 64));
                if (c == 0) mxb[(b0 + j)*8 + w] = m;
            }
            if (w == 0 && c == 0) {
                #pragma unroll
                for (int j = 0; j < 4; ++j) Gb[b0 + j] = G[j];
            }
            __syncthreads();
            #pragma unroll
            for (int j = 0; j < 4; ++j) {
                float XM = -3.0e38f;
                #pragma unroll
                for (int k = 0; k < 8; ++k) XM = fmaxf(XM, mxb[(b0 + j)*8 + k]);
                float sj = fexp2(x[j][0] - XM) + fexp2(x[j][1] - XM)
                         + fexp2(x[j][2] - XM) + fexp2(x[j][3] - XM);
                #pragma unroll
                for (int msk = 1; msk <= 8; msk <<= 1) sj += __shfl_xor(sj, msk, 64);
                if (c == 0) ssum[(b0 + j)*8 + w] = sj;
            }
            __syncthreads();
            if (tid < 16) {
                float S = 0.f, XM = -3.0e38f;
                #pragma unroll
                for (int k = 0; k < 8; ++k) { S += ssum[tid*8 + k]; XM = fmaxf(XM, mxb[tid*8 + k]); }
                part[wg*16 + tid] = LN2 * (Gb[tid] + XM + __log2f(S));
            }
        }
    }
#undef MFMA_K
}

__global__ void crf_final_k(const float* __restrict__ part, float* __restrict__ out)
{
    int t = threadIdx.x;  // 64
    float vsum = part[t] + part[t + 64];
    #pragma unroll
    for (int off = 32; off; off >>= 1) vsum += __shfl_down(vsum, off, 64);
    if (t == 0) out[0] = vsum;
}

extern "C" void kernel_launch(void* const* d_in, const int* in_sizes, int n_in,
                              void* d_out, int out_size, void* d_ws, size_t ws_size,
                              hipStream_t stream)
{
    (void)in_sizes; (void)n_in; (void)out_size; (void)ws_size;
    const float* inp   = (const float*)d_in[0];
    // d_in[1] = tags: unused (partition function only)
    const float* trans = (const float*)d_in[2];
    uint8_t* ws = (uint8_t*)d_ws;
    float* part = (float*)(ws + WS_PART);

    crf_setup_k<<<64, 128, 0, stream>>>(trans, ws);
    crf_main_k<<<8, 512, 0, stream>>>(inp, trans, ws, part);
    crf_final_k<<<1, 64, 0, stream>>>(part, (float*)d_out);
}